// Round 1
// baseline (1127.900 us; speedup 1.0000x reference)
//
#include <hip/hip_runtime.h>
#include <hip/hip_bf16.h>

// ConvNetLayer fused pipeline, MI355X (gfx950).
//
// Factorization: _lin(x[g],W) == _lin(x,W)[g]  -> compute Ux,Vx,Bx,Cx on atoms
// once (bf16 MFMA, weights register-resident), then gather. Pre-BN values go
// f32 straight into d_out and are normalized in place after a deterministic
// two-stage per-column reduction.
//
// Kernel order: A(atom GEMMs) -> B(bond GEMM + gathers + sigmoid + partials)
//   -> C(bond BN stats) -> D(bond finalize) -> E(atom aggregate + partials)
//   -> C(atom BN stats) -> F(atom finalize).

#define H   128
#define NA  300000
#define NB  600000
#define EPS 1e-5f

typedef __attribute__((ext_vector_type(4)))  float  f32x4;
typedef __attribute__((ext_vector_type(16))) float  f32x16;
typedef __attribute__((ext_vector_type(8)))  __bf16 bfv8;

static __device__ __forceinline__ unsigned short f2bf(float f) {
    unsigned u = __float_as_uint(f);
    u = (u + 0x7fffu + ((u >> 16) & 1u)) >> 16;   // RNE
    return (unsigned short)u;
}
static __device__ __forceinline__ float bf2f(unsigned short s) {
    return __uint_as_float(((unsigned)s) << 16);
}

// Load full 128x128 weight as 4(n) x 8(k) register B-fragments for
// v_mfma_f32_32x32x16_bf16.  B frag: lane l holds Wt[k0 + (l>>5)*8 + i][n*32 + (l&31)]
// = W[n*32+(l&31)][k0 + (l>>5)*8 + i]  (8 consecutive f32 of one W row).
static __device__ __forceinline__ void load_w_frags(const float* __restrict__ Wp,
                                                    const float* __restrict__ bp,
                                                    int l31, int khalf,
                                                    bfv8 bw[4][8], float bias_n[4]) {
#pragma unroll
    for (int n = 0; n < 4; n++) {
        bias_n[n] = bp[n * 32 + l31];
        const float* wrow = Wp + (size_t)(n * 32 + l31) * H + khalf * 8;
#pragma unroll
        for (int k = 0; k < 8; k++) {
            f32x4 a0 = *(const f32x4*)(wrow + k * 16);
            f32x4 a1 = *(const f32x4*)(wrow + k * 16 + 4);
            bfv8 f;
#pragma unroll
            for (int i = 0; i < 4; i++) { f[i] = (__bf16)a0[i]; f[i + 4] = (__bf16)a1[i]; }
            bw[n][k] = f;
        }
    }
}

static __device__ __forceinline__ bfv8 load_a_frag(const float* __restrict__ xp) {
    f32x4 a0 = *(const f32x4*)xp;
    f32x4 a1 = *(const f32x4*)(xp + 4);
    bfv8 f;
#pragma unroll
    for (int i = 0; i < 4; i++) { f[i] = (__bf16)a0[i]; f[i + 4] = (__bf16)a1[i]; }
    return f;
}

// ---------------- Kernel A: Ux,Vx,Bx,Cx = lin(X, {U,V,B,C}) as bf16 ----------
// block = 256 thr (4 waves); wave w owns weight w; BM=128 rows/block.
__global__ __launch_bounds__(256, 1) void k_atom_gemm(
    const float* __restrict__ X,
    const float* __restrict__ Uw, const float* __restrict__ Ub,
    const float* __restrict__ Vw, const float* __restrict__ Vb,
    const float* __restrict__ Bw, const float* __restrict__ Bb,
    const float* __restrict__ Cw, const float* __restrict__ Cb,
    unsigned short* __restrict__ Uxo, unsigned short* __restrict__ Vxo,
    unsigned short* __restrict__ Bxo, unsigned short* __restrict__ Cxo)
{
    const int lane  = threadIdx.x & 63;
    const int w     = threadIdx.x >> 6;
    const int l31   = lane & 31;
    const int khalf = lane >> 5;

    const float* Wp; const float* bp; unsigned short* Op;
    if (w == 0)      { Wp = Uw; bp = Ub; Op = Uxo; }
    else if (w == 1) { Wp = Vw; bp = Vb; Op = Vxo; }
    else if (w == 2) { Wp = Bw; bp = Bb; Op = Bxo; }
    else             { Wp = Cw; bp = Cb; Op = Cxo; }

    bfv8 bw[4][8]; float bias_n[4];
    load_w_frags(Wp, bp, l31, khalf, bw, bias_n);

    const int row0 = blockIdx.x * 128;
#pragma unroll 1
    for (int m = 0; m < 4; m++) {
        int row = row0 + m * 32 + l31;
        int rc  = row < NA ? row : NA - 1;
        const float* xp = X + (size_t)rc * H + khalf * 8;

        f32x16 acc[4];
#pragma unroll
        for (int n = 0; n < 4; n++) {
#pragma unroll
            for (int i = 0; i < 16; i++) acc[n][i] = 0.0f;
        }
#pragma unroll
        for (int k = 0; k < 8; k++) {
            bfv8 af = load_a_frag(xp + k * 16);
            acc[0] = __builtin_amdgcn_mfma_f32_32x32x16_bf16(af, bw[0][k], acc[0], 0, 0, 0);
            acc[1] = __builtin_amdgcn_mfma_f32_32x32x16_bf16(af, bw[1][k], acc[1], 0, 0, 0);
            acc[2] = __builtin_amdgcn_mfma_f32_32x32x16_bf16(af, bw[2][k], acc[2], 0, 0, 0);
            acc[3] = __builtin_amdgcn_mfma_f32_32x32x16_bf16(af, bw[3][k], acc[3], 0, 0, 0);
        }
        // C/D layout (verified m74/m101): col = l&31, row = (r&3)+8*(r>>2)+4*(l>>5)
#pragma unroll
        for (int n = 0; n < 4; n++) {
            int col = n * 32 + l31;
#pragma unroll
            for (int r = 0; r < 16; r++) {
                int rl   = (r & 3) + 8 * (r >> 2) + 4 * khalf;
                int orow = row0 + m * 32 + rl;
                if (orow < NA)
                    Op[(size_t)orow * H + col] = f2bf(acc[n][r] + bias_n[n]);
            }
        }
    }
}

// ------------- Kernel B: edge_syn = A*bond + Ab + Bx[g0] + Cx[g1] ------------
// writes f32 edge_syn into d_out bond region, bf16 sigmoid gates into ws,
// per-block per-column BN partials. block = 4 waves, wave w owns rows w*32..+32.
__global__ __launch_bounds__(256, 1) void k_bond_gemm(
    const float* __restrict__ Xb,
    const float* __restrict__ Aw, const float* __restrict__ Ab,
    const int* __restrict__ g2,
    const unsigned short* __restrict__ Bx, const unsigned short* __restrict__ Cx,
    unsigned short* __restrict__ gates,
    float* __restrict__ esyn,
    float* __restrict__ psum, float* __restrict__ psq)
{
    __shared__ float lds_s[4][4][64];
    __shared__ float lds_q[4][4][64];

    const int lane  = threadIdx.x & 63;
    const int w     = threadIdx.x >> 6;
    const int l31   = lane & 31;
    const int khalf = lane >> 5;

    bfv8 bw[4][8]; float bias_n[4];
    load_w_frags(Aw, Ab, l31, khalf, bw, bias_n);

    const int row0 = blockIdx.x * 128 + w * 32;
    int row = row0 + l31;
    int rc  = row < NB ? row : NB - 1;
    const float* xp = Xb + (size_t)rc * H + khalf * 8;

    f32x16 acc[4];
#pragma unroll
    for (int n = 0; n < 4; n++) {
#pragma unroll
        for (int i = 0; i < 16; i++) acc[n][i] = 0.0f;
    }
#pragma unroll
    for (int k = 0; k < 8; k++) {
        bfv8 af = load_a_frag(xp + k * 16);
        acc[0] = __builtin_amdgcn_mfma_f32_32x32x16_bf16(af, bw[0][k], acc[0], 0, 0, 0);
        acc[1] = __builtin_amdgcn_mfma_f32_32x32x16_bf16(af, bw[1][k], acc[1], 0, 0, 0);
        acc[2] = __builtin_amdgcn_mfma_f32_32x32x16_bf16(af, bw[2][k], acc[2], 0, 0, 0);
        acc[3] = __builtin_amdgcn_mfma_f32_32x32x16_bf16(af, bw[3][k], acc[3], 0, 0, 0);
    }

    float s_n[4] = {0.f, 0.f, 0.f, 0.f};
    float q_n[4] = {0.f, 0.f, 0.f, 0.f};
#pragma unroll
    for (int r = 0; r < 16; r++) {
        int rl = (r & 3) + 8 * (r >> 2) + 4 * khalf;
        int e  = row0 + rl;
        if (e < NB) {
            int ga = g2[e * 2 + 0];
            int gb = g2[e * 2 + 1];
#pragma unroll
            for (int n = 0; n < 4; n++) {
                int col = n * 32 + l31;
                float v = acc[n][r] + bias_n[n]
                        + bf2f(Bx[(size_t)ga * H + col])
                        + bf2f(Cx[(size_t)gb * H + col]);
                esyn[(size_t)e * H + col] = v;
                float sg = 1.0f / (1.0f + __expf(-v));
                gates[(size_t)e * H + col] = f2bf(sg);
                s_n[n] += v;
                q_n[n] += v * v;
            }
        }
    }
#pragma unroll
    for (int n = 0; n < 4; n++) { lds_s[w][n][lane] = s_n[n]; lds_q[w][n][lane] = q_n[n]; }
    __syncthreads();
    if (threadIdx.x < 128) {
        int c = threadIdx.x, n = c >> 5, j = c & 31;
        float s = 0.f, q = 0.f;
        for (int ww = 0; ww < 4; ww++) {
            s += lds_s[ww][n][j] + lds_s[ww][n][j + 32];
            q += lds_q[ww][n][j] + lds_q[ww][n][j + 32];
        }
        psum[(size_t)blockIdx.x * H + c] = s;
        psq [(size_t)blockIdx.x * H + c] = q;
    }
}

// ---------------- Kernel C: reduce partials -> scale/shift per column --------
__global__ void k_bn_stats(const float* __restrict__ psum, const float* __restrict__ psq,
                           int nblk, float invN,
                           const float* __restrict__ gamma, const float* __restrict__ beta,
                           float* __restrict__ scale, float* __restrict__ shift)
{
    __shared__ float ls[256], lq[256];
    const int c = blockIdx.x;
    float s = 0.f, q = 0.f;
    for (int i = threadIdx.x; i < nblk; i += 256) {
        s += psum[(size_t)i * H + c];
        q += psq [(size_t)i * H + c];
    }
    ls[threadIdx.x] = s; lq[threadIdx.x] = q;
    __syncthreads();
    for (int off = 128; off > 0; off >>= 1) {
        if ((int)threadIdx.x < off) {
            ls[threadIdx.x] += ls[threadIdx.x + off];
            lq[threadIdx.x] += lq[threadIdx.x + off];
        }
        __syncthreads();
    }
    if (threadIdx.x == 0) {
        float mean = ls[0] * invN;
        float var  = lq[0] * invN - mean * mean;
        float sc   = gamma[c] * rsqrtf(var + EPS);
        scale[c] = sc;
        shift[c] = beta[c] - mean * sc;
    }
}

// ---------------- Kernel D: bond finalize (in place on d_out) ----------------
__global__ void k_bond_out(float* __restrict__ y,
                           const float* __restrict__ scale, const float* __restrict__ shift)
{
    const size_t total = (size_t)NB * H / 4;
    for (size_t i = (size_t)blockIdx.x * blockDim.x + threadIdx.x; i < total;
         i += (size_t)gridDim.x * blockDim.x) {
        f32x4 v = ((const f32x4*)y)[i];
        const f32x4 sc = ((const f32x4*)scale)[i & 31];
        const f32x4 sh = ((const f32x4*)shift)[i & 31];
#pragma unroll
        for (int j = 0; j < 4; j++) v[j] = fmaxf(v[j] * sc[j] + sh[j], 0.0f);
        ((f32x4*)y)[i] = v;
    }
}

// ---------------- Kernel E: atom_syn = Ux + sum_k gate*Vx (gathers) ----------
__global__ void k_atom_msg(const unsigned short* __restrict__ Ux,
                           const unsigned short* __restrict__ Vx,
                           const unsigned short* __restrict__ gates,
                           const int* __restrict__ adj,
                           const int* __restrict__ abadj,
                           float* __restrict__ out_atom,
                           float* __restrict__ psum, float* __restrict__ psq)
{
    const int c  = threadIdx.x & 127;
    const int rh = threadIdx.x >> 7;
    float s = 0.f, q = 0.f;
    for (int r0 = blockIdx.x * 2; r0 < NA; r0 += gridDim.x * 2) {
        int r = r0 + rh;   // NA even -> always < NA
        float v = bf2f(Ux[(size_t)r * H + c]);
#pragma unroll
        for (int k = 0; k < 6; k++) {
            int a = adj[r * 6 + k];
            int b = abadj[r * 6 + k];
            v += bf2f(gates[(size_t)b * H + c]) * bf2f(Vx[(size_t)a * H + c]);
        }
        out_atom[(size_t)r * H + c] = v;
        s += v; q += v * v;
    }
    __shared__ float ls[256], lq[256];
    ls[threadIdx.x] = s; lq[threadIdx.x] = q;
    __syncthreads();
    if (threadIdx.x < 128) {
        psum[(size_t)blockIdx.x * H + threadIdx.x] = ls[threadIdx.x] + ls[threadIdx.x + 128];
        psq [(size_t)blockIdx.x * H + threadIdx.x] = lq[threadIdx.x] + lq[threadIdx.x + 128];
    }
}

// ---------------- Kernel F: atom finalize (in place) + residual --------------
__global__ void k_atom_out(float* __restrict__ y, const float* __restrict__ xin,
                           const float* __restrict__ scale, const float* __restrict__ shift)
{
    const size_t total = (size_t)NA * H / 4;
    for (size_t i = (size_t)blockIdx.x * blockDim.x + threadIdx.x; i < total;
         i += (size_t)gridDim.x * blockDim.x) {
        f32x4 v = ((const f32x4*)y)[i];
        f32x4 x = ((const f32x4*)xin)[i];
        const f32x4 sc = ((const f32x4*)scale)[i & 31];
        const f32x4 sh = ((const f32x4*)shift)[i & 31];
#pragma unroll
        for (int j = 0; j < 4; j++) v[j] = fmaxf(v[j] * sc[j] + sh[j], 0.0f) + x[j];
        ((f32x4*)y)[i] = v;
    }
}

extern "C" void kernel_launch(void* const* d_in, const int* in_sizes, int n_in,
                              void* d_out, int out_size, void* d_ws, size_t ws_size,
                              hipStream_t stream)
{
    const float* X     = (const float*)d_in[0];   // atom_layer_input  (NA,H)
    const float* Xb    = (const float*)d_in[1];   // bond_layer_input  (NB,H)
    const int*   adj   = (const int*)d_in[2];     // (NA,6)
    const int*   abadj = (const int*)d_in[3];     // (NA,6)
    const int*   g2    = (const int*)d_in[4];     // (NB,2)
    const float* Uw = (const float*)d_in[5],  *Ub = (const float*)d_in[6];
    const float* Vw = (const float*)d_in[7],  *Vb = (const float*)d_in[8];
    const float* Aw = (const float*)d_in[9],  *Ab = (const float*)d_in[10];
    const float* Bw = (const float*)d_in[11], *Bb = (const float*)d_in[12];
    const float* Cw = (const float*)d_in[13], *Cb = (const float*)d_in[14];
    const float* gb = (const float*)d_in[15], *bb = (const float*)d_in[16];  // bond BN
    const float* ga = (const float*)d_in[17], *ba = (const float*)d_in[18];  // atom BN

    float* out_atom = (float*)d_out;
    float* out_bond = out_atom + (size_t)NA * H;

    char* ws = (char*)d_ws;
    size_t o = 0;
    unsigned short* Ux    = (unsigned short*)(ws + o); o += (size_t)NA * H * 2;
    unsigned short* Vx    = (unsigned short*)(ws + o); o += (size_t)NA * H * 2;
    unsigned short* Bx    = (unsigned short*)(ws + o); o += (size_t)NA * H * 2;
    unsigned short* Cx    = (unsigned short*)(ws + o); o += (size_t)NA * H * 2;
    unsigned short* gates = (unsigned short*)(ws + o); o += (size_t)NB * H * 2;
    const int GB = (NB + 127) / 128;   // 4688
    float* psum_b = (float*)(ws + o);  o += (size_t)GB * H * 4;
    float* psq_b  = (float*)(ws + o);  o += (size_t)GB * H * 4;
    const int GE = 2048;
    float* psum_a = (float*)(ws + o);  o += (size_t)GE * H * 4;
    float* psq_a  = (float*)(ws + o);  o += (size_t)GE * H * 4;
    float* scale_b = (float*)(ws + o); o += 512;
    float* shift_b = (float*)(ws + o); o += 512;
    float* scale_a = (float*)(ws + o); o += 512;
    float* shift_a = (float*)(ws + o); o += 512;
    (void)o; (void)ws_size; (void)in_sizes; (void)n_in; (void)out_size;

    k_atom_gemm<<<(NA + 127) / 128, 256, 0, stream>>>(X, Uw, Ub, Vw, Vb, Bw, Bb, Cw, Cb,
                                                      Ux, Vx, Bx, Cx);
    k_bond_gemm<<<GB, 256, 0, stream>>>(Xb, Aw, Ab, g2, Bx, Cx, gates, out_bond,
                                        psum_b, psq_b);
    k_bn_stats<<<H, 256, 0, stream>>>(psum_b, psq_b, GB, 1.0f / NB, gb, bb, scale_b, shift_b);
    k_bond_out<<<2048, 256, 0, stream>>>(out_bond, scale_b, shift_b);
    k_atom_msg<<<GE, 256, 0, stream>>>(Ux, Vx, gates, adj, abadj, out_atom, psum_a, psq_a);
    k_bn_stats<<<H, 256, 0, stream>>>(psum_a, psq_a, GE, 1.0f / NA, ga, ba, scale_a, shift_a);
    k_atom_out<<<2048, 256, 0, stream>>>(out_atom, X, scale_a, shift_a);
}

// Round 2
// 983.705 us; speedup vs baseline: 1.1466x; 1.1466x over previous
//
#include <hip/hip_runtime.h>
#include <hip/hip_bf16.h>

// ConvNetLayer fused pipeline, MI355X (gfx950). Round 2.
//
// Factorization: _lin(x[g],W) == _lin(x,W)[g]. Swapped-operand MFMA
// (A=weights, B=activations^T) so each lane owns one output ROW with cols in
// groups of 4 -> all gathers/stores are 8B/16B vector ops. esyn kept bf16
// (gates recomputed on the fly). Persistent GEMM grids, weights in registers.

#define H   128
#define NA  300000
#define NB  600000
#define EPS 1e-5f

#define NTILE_A (NA / 32)   // 9375
#define NTILE_B (NB / 32)   // 18750
#define GEMM_GRID 512
#define EGRID 2048

typedef __attribute__((ext_vector_type(4)))  float  f32x4;
typedef __attribute__((ext_vector_type(16))) float  f32x16;
typedef __attribute__((ext_vector_type(8)))  __bf16 bfv8;
typedef __attribute__((ext_vector_type(4)))  unsigned short u16x4;
typedef __attribute__((ext_vector_type(8)))  unsigned short u16x8;

static __device__ __forceinline__ unsigned short f2bf(float f) {
    unsigned u = __float_as_uint(f);
    u = (u + 0x7fffu + ((u >> 16) & 1u)) >> 16;   // RNE
    return (unsigned short)u;
}
static __device__ __forceinline__ float bf2f(unsigned short s) {
    return __uint_as_float(((unsigned)s) << 16);
}

// Weight fragments (used as MFMA A-operand): lane l holds
// W[n*32 + (l&31)][kf*16 + (l>>5)*8 + i], i=0..7.
static __device__ __forceinline__ void load_w_frags(const float* __restrict__ Wp,
                                                    int l31, int khalf, bfv8 bw[4][8]) {
#pragma unroll
    for (int n = 0; n < 4; n++) {
        const float* wrow = Wp + (size_t)(n * 32 + l31) * H + khalf * 8;
#pragma unroll
        for (int k = 0; k < 8; k++) {
            f32x4 a0 = *(const f32x4*)(wrow + k * 16);
            f32x4 a1 = *(const f32x4*)(wrow + k * 16 + 4);
            bfv8 f;
#pragma unroll
            for (int i = 0; i < 4; i++) { f[i] = (__bf16)a0[i]; f[i + 4] = (__bf16)a1[i]; }
            bw[n][k] = f;
        }
    }
}

// Activation fragment (MFMA B-operand): lane l holds
// X[row(l&31)][kf*16 + (l>>5)*8 + i].
static __device__ __forceinline__ bfv8 load_x_frag(const float* __restrict__ xp) {
    f32x4 a0 = *(const f32x4*)xp;
    f32x4 a1 = *(const f32x4*)(xp + 4);
    bfv8 f;
#pragma unroll
    for (int i = 0; i < 4; i++) { f[i] = (__bf16)a0[i]; f[i + 4] = (__bf16)a1[i]; }
    return f;
}

// ---------------- Kernel A: Ux,Vx,Bx,Cx = lin(X,{U,V,B,C}) bf16 --------------
// 4 waves/block, wave w owns weight w; persistent over atom tiles.
// D^T layout: lane owns atom row (l&31), cols = n*32 + g*8 + 4*khalf + j.
__global__ __launch_bounds__(256, 2) void k_atom_gemm(
    const float* __restrict__ X,
    const float* __restrict__ Uw, const float* __restrict__ Ub,
    const float* __restrict__ Vw, const float* __restrict__ Vb,
    const float* __restrict__ Bw, const float* __restrict__ Bb,
    const float* __restrict__ Cw, const float* __restrict__ Cb,
    unsigned short* __restrict__ Uxo, unsigned short* __restrict__ Vxo,
    unsigned short* __restrict__ Bxo, unsigned short* __restrict__ Cxo)
{
    const int lane  = threadIdx.x & 63;
    const int w     = threadIdx.x >> 6;
    const int l31   = lane & 31;
    const int khalf = lane >> 5;

    const float* Wp; const float* bp; unsigned short* Op;
    if (w == 0)      { Wp = Uw; bp = Ub; Op = Uxo; }
    else if (w == 1) { Wp = Vw; bp = Vb; Op = Vxo; }
    else if (w == 2) { Wp = Bw; bp = Bb; Op = Bxo; }
    else             { Wp = Cw; bp = Cb; Op = Cxo; }

    bfv8 aw[4][8];
    load_w_frags(Wp, l31, khalf, aw);

#pragma unroll 1
    for (int t = blockIdx.x; t < NTILE_A; t += gridDim.x) {
        const int row = t * 32 + l31;                  // atom owned by this lane
        const float* xp = X + (size_t)row * H + khalf * 8;

        bfv8 xf[8];
#pragma unroll
        for (int k = 0; k < 8; k++) xf[k] = load_x_frag(xp + k * 16);

        f32x16 acc[4];
#pragma unroll
        for (int n = 0; n < 4; n++)
#pragma unroll
            for (int i = 0; i < 16; i++) acc[n][i] = 0.0f;

#pragma unroll
        for (int k = 0; k < 8; k++) {
            acc[0] = __builtin_amdgcn_mfma_f32_32x32x16_bf16(aw[0][k], xf[k], acc[0], 0, 0, 0);
            acc[1] = __builtin_amdgcn_mfma_f32_32x32x16_bf16(aw[1][k], xf[k], acc[1], 0, 0, 0);
            acc[2] = __builtin_amdgcn_mfma_f32_32x32x16_bf16(aw[2][k], xf[k], acc[2], 0, 0, 0);
            acc[3] = __builtin_amdgcn_mfma_f32_32x32x16_bf16(aw[3][k], xf[k], acc[3], 0, 0, 0);
        }

        unsigned short* orow = Op + (size_t)row * H;
#pragma unroll
        for (int n = 0; n < 4; n++) {
#pragma unroll
            for (int g = 0; g < 4; g++) {
                const int c0 = n * 32 + g * 8 + khalf * 4;
                f32x4 bv = *(const f32x4*)(bp + c0);
                u16x4 o;
#pragma unroll
                for (int j = 0; j < 4; j++) o[j] = f2bf(acc[n][g * 4 + j] + bv[j]);
                *(u16x4*)(orow + c0) = o;
            }
        }
    }
}

// ------------- Kernel B: esyn = A*bond + Ab + Bx[g0] + Cx[g1]  (bf16) --------
// Each wave is an independent slot sweeping edge tiles.
__global__ __launch_bounds__(256, 2) void k_bond_gemm(
    const float* __restrict__ Xb,
    const float* __restrict__ Aw, const float* __restrict__ Ab,
    const int* __restrict__ g2,
    const unsigned short* __restrict__ Bx, const unsigned short* __restrict__ Cx,
    unsigned short* __restrict__ esyn)
{
    const int lane  = threadIdx.x & 63;
    const int w     = threadIdx.x >> 6;
    const int l31   = lane & 31;
    const int khalf = lane >> 5;

    bfv8 aw[4][8];
    load_w_frags(Aw, l31, khalf, aw);

    const int slot  = blockIdx.x * 4 + w;
    const int nslot = gridDim.x * 4;

#pragma unroll 1
    for (int t = slot; t < NTILE_B; t += nslot) {
        const int e = t * 32 + l31;                    // edge owned by this lane
        const float* xp = Xb + (size_t)e * H + khalf * 8;

        bfv8 xf[8];
#pragma unroll
        for (int k = 0; k < 8; k++) xf[k] = load_x_frag(xp + k * 16);

        f32x16 acc[4];
#pragma unroll
        for (int n = 0; n < 4; n++)
#pragma unroll
            for (int i = 0; i < 16; i++) acc[n][i] = 0.0f;

#pragma unroll
        for (int k = 0; k < 8; k++) {
            acc[0] = __builtin_amdgcn_mfma_f32_32x32x16_bf16(aw[0][k], xf[k], acc[0], 0, 0, 0);
            acc[1] = __builtin_amdgcn_mfma_f32_32x32x16_bf16(aw[1][k], xf[k], acc[1], 0, 0, 0);
            acc[2] = __builtin_amdgcn_mfma_f32_32x32x16_bf16(aw[2][k], xf[k], acc[2], 0, 0, 0);
            acc[3] = __builtin_amdgcn_mfma_f32_32x32x16_bf16(aw[3][k], xf[k], acc[3], 0, 0, 0);
        }

        const int2 gg = *(const int2*)(g2 + 2 * (size_t)e);
        const unsigned short* bxp = Bx + (size_t)gg.x * H;
        const unsigned short* cxp = Cx + (size_t)gg.y * H;
        unsigned short* orow = esyn + (size_t)e * H;
#pragma unroll
        for (int n = 0; n < 4; n++) {
#pragma unroll
            for (int g = 0; g < 4; g++) {
                const int c0 = n * 32 + g * 8 + khalf * 4;
                f32x4 bv = *(const f32x4*)(Ab + c0);
                u16x4 b4 = *(const u16x4*)(bxp + c0);
                u16x4 c4 = *(const u16x4*)(cxp + c0);
                u16x4 o;
#pragma unroll
                for (int j = 0; j < 4; j++) {
                    float v = acc[n][g * 4 + j] + bv[j] + bf2f(b4[j]) + bf2f(c4[j]);
                    o[j] = f2bf(v);
                }
                *(u16x4*)(orow + c0) = o;
            }
        }
    }
}

// ------------- Kernel D1: per-block per-column partial sums over bf16 buf ----
__global__ __launch_bounds__(256) void k_col_stats(const unsigned short* __restrict__ buf,
                                                   long nrows,
                                                   float* __restrict__ psum,
                                                   float* __restrict__ psq)
{
    const size_t total  = (size_t)nrows * (H / 8);
    const size_t stride = (size_t)gridDim.x * 256;     // multiple of 16
    float s[8], q[8];
#pragma unroll
    for (int j = 0; j < 8; j++) { s[j] = 0.f; q[j] = 0.f; }
    for (size_t i = (size_t)blockIdx.x * 256 + threadIdx.x; i < total; i += stride) {
        u16x8 v = ((const u16x8*)buf)[i];
#pragma unroll
        for (int j = 0; j < 8; j++) { float f = bf2f(v[j]); s[j] += f; q[j] += f * f; }
    }
    __shared__ float ls[256][8], lq[256][8];
#pragma unroll
    for (int j = 0; j < 8; j++) { ls[threadIdx.x][j] = s[j]; lq[threadIdx.x][j] = q[j]; }
    __syncthreads();
    if (threadIdx.x < 128) {
        const int c = threadIdx.x, cg = c >> 3, j = c & 7;
        float S = 0.f, Q = 0.f;
        for (int rg = 0; rg < 16; rg++) { S += ls[rg * 16 + cg][j]; Q += lq[rg * 16 + cg][j]; }
        psum[(size_t)blockIdx.x * H + c] = S;
        psq [(size_t)blockIdx.x * H + c] = Q;
    }
}

// ---------------- Kernel C: reduce partials -> per-column scale/shift --------
__global__ void k_bn_stats(const float* __restrict__ psum, const float* __restrict__ psq,
                           int nblk, float invN,
                           const float* __restrict__ gamma, const float* __restrict__ beta,
                           float* __restrict__ scale, float* __restrict__ shift)
{
    __shared__ float ls[256], lq[256];
    const int c = blockIdx.x;
    float s = 0.f, q = 0.f;
    for (int i = threadIdx.x; i < nblk; i += 256) {
        s += psum[(size_t)i * H + c];
        q += psq [(size_t)i * H + c];
    }
    ls[threadIdx.x] = s; lq[threadIdx.x] = q;
    __syncthreads();
    for (int off = 128; off > 0; off >>= 1) {
        if ((int)threadIdx.x < off) {
            ls[threadIdx.x] += ls[threadIdx.x + off];
            lq[threadIdx.x] += lq[threadIdx.x + off];
        }
        __syncthreads();
    }
    if (threadIdx.x == 0) {
        float mean = ls[0] * invN;
        float var  = lq[0] * invN - mean * mean;
        float sc   = gamma[c] * rsqrtf(var + EPS);
        scale[c] = sc;
        shift[c] = beta[c] - mean * sc;
    }
}

// ---------------- Kernel D2: bond finalize  esyn(bf16) -> relu(bn) f32 -------
__global__ __launch_bounds__(256) void k_bond_out(const unsigned short* __restrict__ esyn,
                                                  float* __restrict__ y,
                                                  const float* __restrict__ scale,
                                                  const float* __restrict__ shift)
{
    const size_t total  = (size_t)NB * (H / 8);
    const size_t stride = (size_t)gridDim.x * 256;
    const int c0 = (threadIdx.x & 15) * 8;
    const f32x4 sc0 = *(const f32x4*)(scale + c0), sc1 = *(const f32x4*)(scale + c0 + 4);
    const f32x4 sh0 = *(const f32x4*)(shift + c0), sh1 = *(const f32x4*)(shift + c0 + 4);
    for (size_t i = (size_t)blockIdx.x * 256 + threadIdx.x; i < total; i += stride) {
        u16x8 v = ((const u16x8*)esyn)[i];
        f32x4 o0, o1;
#pragma unroll
        for (int j = 0; j < 4; j++) {
            o0[j] = fmaxf(bf2f(v[j])     * sc0[j] + sh0[j], 0.0f);
            o1[j] = fmaxf(bf2f(v[j + 4]) * sc1[j] + sh1[j], 0.0f);
        }
        ((f32x4*)y)[i * 2]     = o0;
        ((f32x4*)y)[i * 2 + 1] = o1;
    }
}

// -------- Kernel E: atom_syn = Ux + sum_k sigmoid(esyn[b])*Vx[a]  (f32) ------
__global__ __launch_bounds__(256) void k_atom_msg(
    const unsigned short* __restrict__ Ux,
    const unsigned short* __restrict__ Vx,
    const unsigned short* __restrict__ esyn,
    const int* __restrict__ adj,
    const int* __restrict__ abadj,
    float* __restrict__ out_atom,
    float* __restrict__ psum, float* __restrict__ psq)
{
    const int cg = threadIdx.x & 15;
    const int rh = threadIdx.x >> 4;
    const int c0 = cg * 8;
    float s[8], q[8];
#pragma unroll
    for (int j = 0; j < 8; j++) { s[j] = 0.f; q[j] = 0.f; }

    for (int r0 = blockIdx.x * 16; r0 < NA; r0 += gridDim.x * 16) {
        const int r = r0 + rh;
        u16x8 uv = *(const u16x8*)(Ux + (size_t)r * H + c0);
        float v[8];
#pragma unroll
        for (int j = 0; j < 8; j++) v[j] = bf2f(uv[j]);
#pragma unroll
        for (int k = 0; k < 6; k++) {
            const int a = adj[r * 6 + k];
            const int b = abadj[r * 6 + k];
            u16x8 vx = *(const u16x8*)(Vx   + (size_t)a * H + c0);
            u16x8 es = *(const u16x8*)(esyn + (size_t)b * H + c0);
#pragma unroll
            for (int j = 0; j < 8; j++) {
                float g = 1.0f / (1.0f + __expf(-bf2f(es[j])));
                v[j] += g * bf2f(vx[j]);
            }
        }
        f32x4 o0, o1;
#pragma unroll
        for (int j = 0; j < 4; j++) { o0[j] = v[j]; o1[j] = v[j + 4]; }
        float* yp = out_atom + (size_t)r * H + c0;
        *(f32x4*)yp       = o0;
        *(f32x4*)(yp + 4) = o1;
#pragma unroll
        for (int j = 0; j < 8; j++) { s[j] += v[j]; q[j] += v[j] * v[j]; }
    }

    __shared__ float ls[256][8], lq[256][8];
#pragma unroll
    for (int j = 0; j < 8; j++) { ls[threadIdx.x][j] = s[j]; lq[threadIdx.x][j] = q[j]; }
    __syncthreads();
    if (threadIdx.x < 128) {
        const int c = threadIdx.x, g = c >> 3, j = c & 7;
        float S = 0.f, Q = 0.f;
        for (int rg = 0; rg < 16; rg++) { S += ls[rg * 16 + g][j]; Q += lq[rg * 16 + g][j]; }
        psum[(size_t)blockIdx.x * H + c] = S;
        psq [(size_t)blockIdx.x * H + c] = Q;
    }
}

// ---------------- Kernel F: atom finalize (in place on d_out) + residual -----
__global__ __launch_bounds__(256) void k_atom_out(float* __restrict__ y,
                                                  const float* __restrict__ xin,
                                                  const float* __restrict__ scale,
                                                  const float* __restrict__ shift)
{
    const size_t total  = (size_t)NA * (H / 4);
    const size_t stride = (size_t)gridDim.x * 256;
    const int c0 = (threadIdx.x & 31) * 4;
    const f32x4 sc = *(const f32x4*)(scale + c0);
    const f32x4 sh = *(const f32x4*)(shift + c0);
    for (size_t i = (size_t)blockIdx.x * 256 + threadIdx.x; i < total; i += stride) {
        f32x4 v = ((const f32x4*)y)[i];
        f32x4 x = ((const f32x4*)xin)[i];
#pragma unroll
        for (int j = 0; j < 4; j++) v[j] = fmaxf(v[j] * sc[j] + sh[j], 0.0f) + x[j];
        ((f32x4*)y)[i] = v;
    }
}

extern "C" void kernel_launch(void* const* d_in, const int* in_sizes, int n_in,
                              void* d_out, int out_size, void* d_ws, size_t ws_size,
                              hipStream_t stream)
{
    const float* X     = (const float*)d_in[0];
    const float* Xb    = (const float*)d_in[1];
    const int*   adj   = (const int*)d_in[2];
    const int*   abadj = (const int*)d_in[3];
    const int*   g2    = (const int*)d_in[4];
    const float* Uw = (const float*)d_in[5],  *Ub = (const float*)d_in[6];
    const float* Vw = (const float*)d_in[7],  *Vb = (const float*)d_in[8];
    const float* Aw = (const float*)d_in[9],  *Ab = (const float*)d_in[10];
    const float* Bw = (const float*)d_in[11], *Bb = (const float*)d_in[12];
    const float* Cw = (const float*)d_in[13], *Cb = (const float*)d_in[14];
    const float* gb = (const float*)d_in[15], *bb = (const float*)d_in[16];
    const float* ga = (const float*)d_in[17], *ba = (const float*)d_in[18];

    float* out_atom = (float*)d_out;
    float* out_bond = out_atom + (size_t)NA * H;

    char* ws = (char*)d_ws;
    size_t o = 0;
    unsigned short* Ux    = (unsigned short*)(ws + o); o += (size_t)NA * H * 2;
    unsigned short* Vx    = (unsigned short*)(ws + o); o += (size_t)NA * H * 2;
    unsigned short* Bx    = (unsigned short*)(ws + o); o += (size_t)NA * H * 2;
    unsigned short* Cx    = (unsigned short*)(ws + o); o += (size_t)NA * H * 2;
    unsigned short* esyn  = (unsigned short*)(ws + o); o += (size_t)NB * H * 2;
    float* psum_b = (float*)(ws + o);  o += (size_t)EGRID * H * 4;
    float* psq_b  = (float*)(ws + o);  o += (size_t)EGRID * H * 4;
    float* psum_a = (float*)(ws + o);  o += (size_t)EGRID * H * 4;
    float* psq_a  = (float*)(ws + o);  o += (size_t)EGRID * H * 4;
    float* scale_b = (float*)(ws + o); o += 512;
    float* shift_b = (float*)(ws + o); o += 512;
    float* scale_a = (float*)(ws + o); o += 512;
    float* shift_a = (float*)(ws + o); o += 512;
    (void)o; (void)ws_size; (void)in_sizes; (void)n_in; (void)out_size;

    k_atom_gemm<<<GEMM_GRID, 256, 0, stream>>>(X, Uw, Ub, Vw, Vb, Bw, Bb, Cw, Cb,
                                               Ux, Vx, Bx, Cx);
    k_bond_gemm<<<GEMM_GRID, 256, 0, stream>>>(Xb, Aw, Ab, g2, Bx, Cx, esyn);
    k_col_stats<<<EGRID, 256, 0, stream>>>(esyn, NB, psum_b, psq_b);
    k_bn_stats<<<H, 256, 0, stream>>>(psum_b, psq_b, EGRID, 1.0f / NB, gb, bb, scale_b, shift_b);
    k_bond_out<<<EGRID, 256, 0, stream>>>(esyn, out_bond, scale_b, shift_b);
    k_atom_msg<<<EGRID, 256, 0, stream>>>(Ux, Vx, esyn, adj, abadj, out_atom, psum_a, psq_a);
    k_bn_stats<<<H, 256, 0, stream>>>(psum_a, psq_a, EGRID, 1.0f / NA, ga, ba, scale_a, shift_a);
    k_atom_out<<<2048, 256, 0, stream>>>(out_atom, X, scale_a, shift_a);
}